// Round 1
// baseline (249.015 us; speedup 1.0000x reference)
//
#include <hip/hip_runtime.h>

// ExponentialUnitNorm, single-kernel decoupled-lookback scan:
//   phase1: per-chunk local partial B[b,c,f]   (reads x from HBM, 123 MB)
//   sync:   value-is-flag publish of B via agent-scope atomics into `part`
//           (pre-poisoned to -NaN by hipMemsetAsync; valid partials are > 0
//           since magnitudes are clamped at sqrt(1e-14))
//   lookback: windowed over ALL predecessors j<c (no serial chain):
//           S_c = sum_{j<c} aL^(c-1-j) B_j + aL^c * init   (same recurrence
//           the old eun_mid kernel computed, just fused in-kernel)
//   phase2: rescan chunk (x is L3-resident on re-read; NT-stores of `out`
//           bypass L2/L3 so x is never evicted), normalize, NT-store.
// Deadlock-safe: no LDS, low VGPR -> ~2000 co-resident blocks >= 1600 grid
// blocks, and blocks only wait on lower-ID (earlier-dispatched) blocks;
// grid z = chunk index is the slowest dispatch dimension.
// Comparison is bf16-quantized; fp reassociation is far below threshold
// (previous 3-kernel version with identical math measured absmax 0.03125
// = 1 bf16 ulp).

#define ALPHA_F 0.99f
#define OMA_F   0.01f
#define EPS_F   1e-14f

constexpr int Bn = 16;
constexpr int Tn = 2000;
constexpr int Fn = 481;
constexpr int NC = 50;          // chunks along T
constexpr int L  = Tn / NC;     // 40
constexpr int UN = 10;          // unroll batch; L % UN == 0
#define ALPHA_L 0.668971758f    // 0.99^40

__global__ __launch_bounds__(256) void eun_fused(
    const float* __restrict__ x, const float* __restrict__ init_state,
    float* __restrict__ out, float* __restrict__ part) {
  const int f = blockIdx.x * blockDim.x + threadIdx.x;
  if (f >= Fn) return;
  const int b = blockIdx.y;
  const int c = blockIdx.z;

  const size_t stride = (size_t)Fn * 2;
  const size_t off = ((size_t)b * Tn + (size_t)c * L) * stride + (size_t)f * 2;

  // ---- Phase 1: local partial over this chunk (x from HBM) ----
  const float* xp = x + off;
  float p = 0.f;
  for (int t0 = 0; t0 < L; t0 += UN) {
    float2 v[UN];
#pragma unroll
    for (int j = 0; j < UN; ++j)
      v[j] = *(const float2*)(xp + (size_t)j * stride);
#pragma unroll
    for (int j = 0; j < UN; ++j) {
      float m = sqrtf(fmaxf(fmaf(v[j].x, v[j].x, v[j].y * v[j].y), EPS_F));
      p = fmaf(ALPHA_F, p, OMA_F * m);
    }
    xp += (size_t)UN * stride;
  }

  // ---- Publish partial (value-is-flag; p >= 0.01*0.99^39*1e-7 > 0) ----
  float* pb = part + (size_t)b * NC * Fn + f;  // this (b,f) column
  __hip_atomic_store(pb + (size_t)c * Fn, p,
                     __ATOMIC_RELAXED, __HIP_MEMORY_SCOPE_AGENT);

  // ---- Windowed lookback: S = sum_{j<c} aL^(c-1-j) B_j + aL^c * init ----
  float acc = 0.f, w = 1.f;
  for (int j = c - 1; j >= 0; --j) {
    float pv = __hip_atomic_load(pb + (size_t)j * Fn,
                                 __ATOMIC_RELAXED, __HIP_MEMORY_SCOPE_AGENT);
    while (!(pv > 0.f)) {   // poison is -NaN: (-NaN > 0) is false
      __builtin_amdgcn_s_sleep(1);
      pv = __hip_atomic_load(pb + (size_t)j * Fn,
                             __ATOMIC_RELAXED, __HIP_MEMORY_SCOPE_AGENT);
    }
    acc = fmaf(w, pv, acc);
    w *= ALPHA_L;
  }
  float s = fmaf(w, init_state[f], acc);

  // ---- Phase 2: rescan (x L3-resident), normalize, NT-store ----
  xp = x + off;
  float* op = out + off;
  for (int t0 = 0; t0 < L; t0 += UN) {
    float2 v[UN];
#pragma unroll
    for (int j = 0; j < UN; ++j)
      v[j] = *(const float2*)(xp + (size_t)j * stride);
#pragma unroll
    for (int j = 0; j < UN; ++j) {
      float m = sqrtf(fmaxf(fmaf(v[j].x, v[j].x, v[j].y * v[j].y), EPS_F));
      s = fmaf(ALPHA_F, s, OMA_F * m);
      float inv = rsqrtf(s);
      union { float2 f2; unsigned long long u; } cvt;
      cvt.f2 = make_float2(v[j].x * inv, v[j].y * inv);
      // out is never re-read: bypass L2/L3 so x stays cache-resident.
      __builtin_nontemporal_store(cvt.u,
          (unsigned long long*)(op + (size_t)j * stride));
    }
    xp += (size_t)UN * stride;
    op += (size_t)UN * stride;
  }
}

extern "C" void kernel_launch(void* const* d_in, const int* in_sizes, int n_in,
                              void* d_out, int out_size, void* d_ws, size_t ws_size,
                              hipStream_t stream) {
  const float* x    = (const float*)d_in[0];
  const float* init = (const float*)d_in[1];
  float* out        = (float*)d_out;
  float* part       = (float*)d_ws;  // Bn*NC*Fn floats = 1.54 MB

  // Poison partials to 0xFFFFFFFF (-NaN) so "value > 0" is the ready flag.
  hipMemsetAsync(part, 0xFF, (size_t)Bn * NC * Fn * sizeof(float), stream);

  dim3 grid((Fn + 255) / 256, Bn, NC);  // z (chunk) = slowest dispatch dim
  eun_fused<<<grid, dim3(256), 0, stream>>>(x, init, out, part);
}